// Round 9
// baseline (385.494 us; speedup 1.0000x reference)
//
#include <hip/hip_runtime.h>

#define D 96

// ---------------- CSR build ----------------

__global__ void count_kernel(const int* __restrict__ ei, int* __restrict__ cnt, int e) {
    int i = blockIdx.x * 256 + threadIdx.x;
    if (i < e) atomicAdd(&cnt[ei[e + i]], 1);   // dst row of edge_index
}

__global__ void scan_blocks(const int* __restrict__ cnt, int* __restrict__ rp,
                            int* __restrict__ bsums, int n) {
    __shared__ int s[256];
    int i = blockIdx.x * 256 + threadIdx.x;
    int v = (i < n) ? cnt[i] : 0;
    s[threadIdx.x] = v;
    __syncthreads();
    for (int off = 1; off < 256; off <<= 1) {
        int t = (threadIdx.x >= off) ? s[threadIdx.x - off] : 0;
        __syncthreads();
        s[threadIdx.x] += t;
        __syncthreads();
    }
    if (i < n) rp[i] = s[threadIdx.x] - v;          // exclusive within block
    if (threadIdx.x == 255) bsums[blockIdx.x] = s[255];
}

__global__ void scan_sums(int* __restrict__ bsums, int nb) {
    __shared__ int s[512];
    int t = threadIdx.x;
    int v = (t < nb) ? bsums[t] : 0;
    s[t] = v;
    __syncthreads();
    for (int off = 1; off < 512; off <<= 1) {
        int u = (t >= off) ? s[t - off] : 0;
        __syncthreads();
        s[t] += u;
        __syncthreads();
    }
    if (t < nb) bsums[t] = s[t] - v;                // exclusive block offsets
}

__global__ void add_offsets(int* __restrict__ rp, const int* __restrict__ bsums, int n) {
    int i = blockIdx.x * 256 + threadIdx.x;
    if (i < n) rp[i] += bsums[blockIdx.x];
}

__global__ void dis_kernel(const int* __restrict__ cnt, float* __restrict__ dis,
                           int n, int* __restrict__ rp, int e) {
    int i = blockIdx.x * 256 + threadIdx.x;
    if (i < n) dis[i] = rsqrtf((float)(cnt[i] + 1));   // +1 self-loop
    if (i == 0) rp[n] = e;
}

// single random access per edge: rpc is a consumable cursor copy of rp
__global__ void scatter_kernel(const int* __restrict__ ei, int* __restrict__ rpc,
                               int* __restrict__ esrc, int e) {
    int i = blockIdx.x * 256 + threadIdx.x;
    if (i < e) {
        int pos = atomicAdd(&rpc[ei[e + i]], 1);   // dst cursor
        esrc[pos] = ei[i];                         // src
    }
}

// ---------------- one-shot W transpose: Wt[c][k] = W[k][c] ----------------

__global__ void wt_kernel(const float* __restrict__ W1, const float* __restrict__ W2,
                          float* __restrict__ Wt1, float* __restrict__ Wt2) {
    int i = blockIdx.x * 256 + threadIdx.x;
    if (i < D * D) {
        int k = i / D, c = i % D;
        Wt1[c * D + k] = W1[i];
        Wt2[c * D + k] = W2[i];
    }
}

// ---------------- hs = dis[row] * (X @ W) ----------------
// 256 threads: 128 rows x 96 cols per block; 8x6 register tile per thread.
// __launch_bounds__(256) ONLY: R8 showed (256,4) made the allocator target
// 8 waves/SIMD (VGPR=64) and spill the ~110-reg live set to scratch
// (WRITE_SIZE 51MB vs 38.4 ideal). Let it keep ~120 regs, ~3 blocks/CU.

#define KC 32
#define XS_S 36
#define WT_S 36

__global__ __launch_bounds__(256) void gemm_scale(const float* __restrict__ X,
                                                  const float* __restrict__ Wt,
                                                  const float* __restrict__ dis,
                                                  float* __restrict__ out, int n) {
    __shared__ float xs[128 * XS_S];   // 18432 B
    __shared__ float wt[96 * WT_S];    // 13824 B
    int t = threadIdx.x;
    int row0 = blockIdx.x * 128;
    int rg = t & 15;      // rows rg*8 .. +7
    int cg = t >> 4;      // cols cg*6 .. +5
    float acc[8][6] = {};

    for (int kc = 0; kc < D; kc += KC) {
        for (int i = t; i < 96 * 8; i += 256) {            // wt chunk
            int c = i >> 3, c4 = i & 7;
            float4 v = *(const float4*)&Wt[c * D + kc + c4 * 4];
            *(float4*)&wt[c * WT_S + c4 * 4] = v;
        }
        for (int i = t; i < 128 * 8; i += 256) {           // xs chunk (swizzled)
            int r = i >> 3, c4 = i & 7;
            int gr = row0 + r;
            float4 v = (gr < n) ? *(const float4*)&X[(size_t)gr * D + kc + c4 * 4]
                                : make_float4(0.f, 0.f, 0.f, 0.f);
            *(float4*)&xs[r * XS_S + 4 * (c4 ^ ((r >> 3) & 7))] = v;
        }
        __syncthreads();
        #pragma unroll
        for (int k4 = 0; k4 < 8; ++k4) {
            float4 a[8], b[6];
            int xk = 4 * (k4 ^ (rg & 7));
            #pragma unroll
            for (int i = 0; i < 8; ++i)
                a[i] = *(const float4*)&xs[(rg * 8 + i) * XS_S + xk];
            #pragma unroll
            for (int j = 0; j < 6; ++j)
                b[j] = *(const float4*)&wt[(cg * 6 + j) * WT_S + k4 * 4];
            #pragma unroll
            for (int i = 0; i < 8; ++i)
                #pragma unroll
                for (int j = 0; j < 6; ++j) {
                    acc[i][j] += a[i].x * b[j].x;
                    acc[i][j] += a[i].y * b[j].y;
                    acc[i][j] += a[i].z * b[j].z;
                    acc[i][j] += a[i].w * b[j].w;
                }
        }
        __syncthreads();
    }
    #pragma unroll
    for (int i = 0; i < 8; ++i) {
        int gr = row0 + rg * 8 + i;
        if (gr < n) {
            float dsc = dis[gr];
            #pragma unroll
            for (int j = 0; j < 6; ++j)
                out[(size_t)gr * D + cg * 6 + j] = dsc * acc[i][j];
        }
    }
}

// ---------------- out = relu(dis[i]*(hs[i] + sum_{e:dst=i} hs[src]) + b) ----------------
// 24 active lanes per 32-lane node-group, one float4 per lane (24*16B = 384B row).
// 2-way edge unroll with dual accumulators for memory-level parallelism.

__global__ __launch_bounds__(256) void agg_kernel(const float* __restrict__ hs,
                                                  const float* __restrict__ dis,
                                                  const float* __restrict__ bias,
                                                  const int* __restrict__ rp,
                                                  const int* __restrict__ esrc,
                                                  float* __restrict__ out, int n) {
    int lane = threadIdx.x & 31;
    int node = blockIdx.x * 8 + (threadIdx.x >> 5);
    if (node >= n || lane >= 24) return;
    float4 s = ((const float4*)(hs + (size_t)node * D))[lane];   // self-loop term
    float4 s2 = make_float4(0.f, 0.f, 0.f, 0.f);
    int beg = rp[node], end = rp[node + 1];
    int e = beg;
    for (; e + 1 < end; e += 2) {
        float4 v0 = ((const float4*)(hs + (size_t)esrc[e] * D))[lane];
        float4 v1 = ((const float4*)(hs + (size_t)esrc[e + 1] * D))[lane];
        s.x += v0.x;  s.y += v0.y;  s.z += v0.z;  s.w += v0.w;
        s2.x += v1.x; s2.y += v1.y; s2.z += v1.z; s2.w += v1.w;
    }
    if (e < end) {
        float4 v0 = ((const float4*)(hs + (size_t)esrc[e] * D))[lane];
        s.x += v0.x; s.y += v0.y; s.z += v0.z; s.w += v0.w;
    }
    float dsc = dis[node];
    float4 b = ((const float4*)bias)[lane];
    float4 o;
    o.x = fmaxf(dsc * (s.x + s2.x) + b.x, 0.f);
    o.y = fmaxf(dsc * (s.y + s2.y) + b.y, 0.f);
    o.z = fmaxf(dsc * (s.z + s2.z) + b.z, 0.f);
    o.w = fmaxf(dsc * (s.w + s2.w) + b.w, 0.f);
    ((float4*)(out + (size_t)node * D))[lane] = o;
}

extern "C" void kernel_launch(void* const* d_in, const int* in_sizes, int n_in,
                              void* d_out, int out_size, void* d_ws, size_t ws_size,
                              hipStream_t stream) {
    const float* x  = (const float*)d_in[0];
    const int*   ei = (const int*)d_in[1];
    const float* W1 = (const float*)d_in[2];
    const float* b1 = (const float*)d_in[3];
    const float* W2 = (const float*)d_in[4];
    const float* b2 = (const float*)d_in[5];
    float* out = (float*)d_out;
    int n = in_sizes[0] / D;
    int e = in_sizes[1] / 2;

    char* ws = (char*)d_ws;
    size_t off = 0;
    auto take = [&](size_t bytes) {
        char* p = ws + off;
        off += (bytes + 511) & ~511ULL;
        return p;
    };
    int*   cnt   = (int*)take((size_t)n * 4);
    int*   rp    = (int*)take((size_t)(n + 1) * 4);
    int*   rpc   = (int*)take((size_t)n * 4);
    int*   bsums = (int*)take(512 * 4);
    float* dsc   = (float*)take((size_t)n * 4);
    float* Wt1   = (float*)take((size_t)D * D * 4);
    float* Wt2   = (float*)take((size_t)D * D * 4);
    int*   esrc  = (int*)take((size_t)e * 4);
    float* A     = (float*)take((size_t)n * D * 4);
    float* B     = (float*)take((size_t)n * D * 4);

    hipMemsetAsync(cnt, 0, (size_t)n * 4, stream);

    int nbE = (e + 255) / 256;
    int nbN = (n + 255) / 256;
    count_kernel<<<nbE, 256, 0, stream>>>(ei, cnt, e);
    scan_blocks<<<nbN, 256, 0, stream>>>(cnt, rp, bsums, n);
    scan_sums<<<1, 512, 0, stream>>>(bsums, nbN);
    add_offsets<<<nbN, 256, 0, stream>>>(rp, bsums, n);
    dis_kernel<<<nbN, 256, 0, stream>>>(cnt, dsc, n, rp, e);
    hipMemcpyAsync(rpc, rp, (size_t)n * 4, hipMemcpyDeviceToDevice, stream);
    scatter_kernel<<<nbE, 256, 0, stream>>>(ei, rpc, esrc, e);
    wt_kernel<<<(2 * D * D + 255) / 256, 256, 0, stream>>>(W1, W2, Wt1, Wt2);

    int nbG = (n + 127) / 128;
    gemm_scale<<<nbG, 256, 0, stream>>>(x, Wt1, dsc, A, n);
    agg_kernel<<<(n + 7) / 8, 256, 0, stream>>>(A, dsc, b1, rp, esrc, B, n);
    gemm_scale<<<nbG, 256, 0, stream>>>(B, Wt2, dsc, A, n);
    agg_kernel<<<(n + 7) / 8, 256, 0, stream>>>(A, dsc, b2, rp, esrc, out, n);
}

// Round 10
// 325.073 us; speedup vs baseline: 1.1859x; 1.1859x over previous
//
#include <hip/hip_runtime.h>

#define D 96
#define BSH 9          // 512 nodes per bucket
#define BNODES 512
#define MAXBUK 256     // supports n <= 131072

// ---------------- bucket-partition CSR build ----------------

// P1: global bucket histogram (LDS-aggregated)
__global__ __launch_bounds__(256) void p1_hist(const int* __restrict__ ei,
                                               int* __restrict__ bcnt, int e) {
    __shared__ int h[MAXBUK];
    for (int i = threadIdx.x; i < MAXBUK; i += 256) h[i] = 0;
    __syncthreads();
    for (int i = blockIdx.x * 256 + threadIdx.x; i < e; i += gridDim.x * 256)
        atomicAdd(&h[ei[e + i] >> BSH], 1);
    __syncthreads();
    for (int i = threadIdx.x; i < MAXBUK; i += 256)
        if (h[i]) atomicAdd(&bcnt[i], h[i]);
}

// P1b: exclusive scan of bucket counts -> bbase[257]; init reservation cursors
__global__ void p1_scan(const int* __restrict__ bcnt, int* __restrict__ bbase,
                        int* __restrict__ bcur, int e, int nbuk) {
    __shared__ int s[MAXBUK];
    int t = threadIdx.x;
    int v = (t < nbuk) ? bcnt[t] : 0;
    s[t] = v;
    __syncthreads();
    for (int off = 1; off < MAXBUK; off <<= 1) {
        int u = (t >= off) ? s[t - off] : 0;
        __syncthreads();
        s[t] += u;
        __syncthreads();
    }
    int ex = s[t] - v;           // for t >= nbuk this equals e (empty buckets)
    bbase[t] = ex;
    bcur[t] = ex;
    if (t == MAXBUK - 1) bbase[MAXBUK] = e;
}

// P2: partition edges into bucket-grouped (dst,src) pairs; per-block chunk reservation
__global__ __launch_bounds__(256) void p2_part(const int* __restrict__ ei,
                                               int* __restrict__ bcur,
                                               int2* __restrict__ pairs, int e) {
    __shared__ int h[MAXBUK];
    __shared__ int base[MAXBUK];
    __shared__ int offs[MAXBUK];
    const int CHUNK = 8192;
    int begin = blockIdx.x * CHUNK;
    int endc = min(begin + CHUNK, e);
    for (int i = threadIdx.x; i < MAXBUK; i += 256) h[i] = 0;
    __syncthreads();
    for (int i = begin + threadIdx.x; i < endc; i += 256)
        atomicAdd(&h[ei[e + i] >> BSH], 1);
    __syncthreads();
    for (int i = threadIdx.x; i < MAXBUK; i += 256) {
        int c = h[i];
        base[i] = c ? atomicAdd(&bcur[i], c) : 0;
        offs[i] = 0;
    }
    __syncthreads();
    for (int i = begin + threadIdx.x; i < endc; i += 256) {
        int d = ei[e + i], sv = ei[i];
        int b = d >> BSH;
        int r = atomicAdd(&offs[b], 1);
        pairs[base[b] + r] = make_int2(d, sv);
    }
}

// P3: one block per bucket: degrees + scan in LDS -> rp, dis, esrc (L2-hot region)
__global__ __launch_bounds__(256) void p3_build(const int2* __restrict__ pairs,
                                                const int* __restrict__ bbase,
                                                int* __restrict__ rp, float* __restrict__ dis,
                                                int* __restrict__ esrc, int n, int e) {
    __shared__ int deg[BNODES];
    __shared__ int cur[BNODES];
    __shared__ int ps[256];
    int b = blockIdx.x;
    int node0 = b << BSH;
    int t = threadIdx.x;
    int pbeg = bbase[b], pend = bbase[b + 1];
    deg[t] = 0; deg[t + 256] = 0;
    __syncthreads();
    for (int i = pbeg + t; i < pend; i += 256)
        atomicAdd(&deg[pairs[i].x - node0], 1);
    __syncthreads();
    int d0 = deg[2 * t], d1 = deg[2 * t + 1];
    int pv = d0 + d1;
    ps[t] = pv;
    __syncthreads();
    for (int off = 1; off < 256; off <<= 1) {
        int u = (t >= off) ? ps[t - off] : 0;
        __syncthreads();
        ps[t] += u;
        __syncthreads();
    }
    int ex = ps[t] - pv;                 // exclusive base of node 2t within bucket
    int e0 = ex, e1 = ex + d0;
    cur[2 * t] = e0; cur[2 * t + 1] = e1;
    int n0 = node0 + 2 * t, n1 = n0 + 1;
    if (n0 < n) { rp[n0] = pbeg + e0; dis[n0] = rsqrtf((float)(d0 + 1)); }
    if (n1 < n) { rp[n1] = pbeg + e1; dis[n1] = rsqrtf((float)(d1 + 1)); }
    if (b == 0 && t == 0) rp[n] = e;
    __syncthreads();
    for (int i = pbeg + t; i < pend; i += 256) {
        int2 p = pairs[i];
        int r = atomicAdd(&cur[p.x - node0], 1);
        esrc[pbeg + r] = p.y;
    }
}

// ---------------- one-shot W transpose: Wt[c][k] = W[k][c] ----------------

__global__ void wt_kernel(const float* __restrict__ W1, const float* __restrict__ W2,
                          float* __restrict__ Wt1, float* __restrict__ Wt2) {
    int i = blockIdx.x * 256 + threadIdx.x;
    if (i < D * D) {
        int k = i / D, c = i % D;
        Wt1[c * D + k] = W1[i];
        Wt2[c * D + k] = W2[i];
    }
}

// ---------------- hs = dis[row] * (X @ W) ----------------
// UNCHANGED from R9 (surfacing in top-5 next bench will expose its VGPR/occupancy).

#define KC 32
#define XS_S 36
#define WT_S 36

__global__ __launch_bounds__(256) void gemm_scale(const float* __restrict__ X,
                                                  const float* __restrict__ Wt,
                                                  const float* __restrict__ dis,
                                                  float* __restrict__ out, int n) {
    __shared__ float xs[128 * XS_S];   // 18432 B
    __shared__ float wt[96 * WT_S];    // 13824 B
    int t = threadIdx.x;
    int row0 = blockIdx.x * 128;
    int rg = t & 15;      // rows rg*8 .. +7
    int cg = t >> 4;      // cols cg*6 .. +5
    float acc[8][6] = {};

    for (int kc = 0; kc < D; kc += KC) {
        for (int i = t; i < 96 * 8; i += 256) {            // wt chunk
            int c = i >> 3, c4 = i & 7;
            float4 v = *(const float4*)&Wt[c * D + kc + c4 * 4];
            *(float4*)&wt[c * WT_S + c4 * 4] = v;
        }
        for (int i = t; i < 128 * 8; i += 256) {           // xs chunk (swizzled)
            int r = i >> 3, c4 = i & 7;
            int gr = row0 + r;
            float4 v = (gr < n) ? *(const float4*)&X[(size_t)gr * D + kc + c4 * 4]
                                : make_float4(0.f, 0.f, 0.f, 0.f);
            *(float4*)&xs[r * XS_S + 4 * (c4 ^ ((r >> 3) & 7))] = v;
        }
        __syncthreads();
        #pragma unroll
        for (int k4 = 0; k4 < 8; ++k4) {
            float4 a[8], b[6];
            int xk = 4 * (k4 ^ (rg & 7));
            #pragma unroll
            for (int i = 0; i < 8; ++i)
                a[i] = *(const float4*)&xs[(rg * 8 + i) * XS_S + xk];
            #pragma unroll
            for (int j = 0; j < 6; ++j)
                b[j] = *(const float4*)&wt[(cg * 6 + j) * WT_S + k4 * 4];
            #pragma unroll
            for (int i = 0; i < 8; ++i)
                #pragma unroll
                for (int j = 0; j < 6; ++j) {
                    acc[i][j] += a[i].x * b[j].x;
                    acc[i][j] += a[i].y * b[j].y;
                    acc[i][j] += a[i].z * b[j].z;
                    acc[i][j] += a[i].w * b[j].w;
                }
        }
        __syncthreads();
    }
    #pragma unroll
    for (int i = 0; i < 8; ++i) {
        int gr = row0 + rg * 8 + i;
        if (gr < n) {
            float dsc = dis[gr];
            #pragma unroll
            for (int j = 0; j < 6; ++j)
                out[(size_t)gr * D + cg * 6 + j] = dsc * acc[i][j];
        }
    }
}

// ---------------- out = relu(dis[i]*(hs[i] + sum_{e:dst=i} hs[src]) + b) ----------------
// UNCHANGED from R9.

__global__ __launch_bounds__(256) void agg_kernel(const float* __restrict__ hs,
                                                  const float* __restrict__ dis,
                                                  const float* __restrict__ bias,
                                                  const int* __restrict__ rp,
                                                  const int* __restrict__ esrc,
                                                  float* __restrict__ out, int n) {
    int lane = threadIdx.x & 31;
    int node = blockIdx.x * 8 + (threadIdx.x >> 5);
    if (node >= n || lane >= 24) return;
    float4 s = ((const float4*)(hs + (size_t)node * D))[lane];   // self-loop term
    float4 s2 = make_float4(0.f, 0.f, 0.f, 0.f);
    int beg = rp[node], end = rp[node + 1];
    int e = beg;
    for (; e + 1 < end; e += 2) {
        float4 v0 = ((const float4*)(hs + (size_t)esrc[e] * D))[lane];
        float4 v1 = ((const float4*)(hs + (size_t)esrc[e + 1] * D))[lane];
        s.x += v0.x;  s.y += v0.y;  s.z += v0.z;  s.w += v0.w;
        s2.x += v1.x; s2.y += v1.y; s2.z += v1.z; s2.w += v1.w;
    }
    if (e < end) {
        float4 v0 = ((const float4*)(hs + (size_t)esrc[e] * D))[lane];
        s.x += v0.x; s.y += v0.y; s.z += v0.z; s.w += v0.w;
    }
    float dsc = dis[node];
    float4 b = ((const float4*)bias)[lane];
    float4 o;
    o.x = fmaxf(dsc * (s.x + s2.x) + b.x, 0.f);
    o.y = fmaxf(dsc * (s.y + s2.y) + b.y, 0.f);
    o.z = fmaxf(dsc * (s.z + s2.z) + b.z, 0.f);
    o.w = fmaxf(dsc * (s.w + s2.w) + b.w, 0.f);
    ((float4*)(out + (size_t)node * D))[lane] = o;
}

extern "C" void kernel_launch(void* const* d_in, const int* in_sizes, int n_in,
                              void* d_out, int out_size, void* d_ws, size_t ws_size,
                              hipStream_t stream) {
    const float* x  = (const float*)d_in[0];
    const int*   ei = (const int*)d_in[1];
    const float* W1 = (const float*)d_in[2];
    const float* b1 = (const float*)d_in[3];
    const float* W2 = (const float*)d_in[4];
    const float* b2 = (const float*)d_in[5];
    float* out = (float*)d_out;
    int n = in_sizes[0] / D;
    int e = in_sizes[1] / 2;
    int nbuk = (n + BNODES - 1) >> BSH;

    char* ws = (char*)d_ws;
    size_t off = 0;
    auto take = [&](size_t bytes) {
        char* p = ws + off;
        off += (bytes + 511) & ~511ULL;
        return p;
    };
    int*   bcnt  = (int*)take(MAXBUK * 4);
    int*   bbase = (int*)take((MAXBUK + 1) * 4);
    int*   bcur  = (int*)take(MAXBUK * 4);
    int2*  pairs = (int2*)take((size_t)e * 8);
    int*   rp    = (int*)take((size_t)(n + 1) * 4);
    float* dsc   = (float*)take((size_t)n * 4);
    float* Wt1   = (float*)take((size_t)D * D * 4);
    float* Wt2   = (float*)take((size_t)D * D * 4);
    int*   esrc  = (int*)take((size_t)e * 4);
    float* A     = (float*)take((size_t)n * D * 4);
    float* B     = (float*)take((size_t)n * D * 4);

    hipMemsetAsync(bcnt, 0, MAXBUK * 4, stream);

    p1_hist<<<256, 256, 0, stream>>>(ei, bcnt, e);
    p1_scan<<<1, MAXBUK, 0, stream>>>(bcnt, bbase, bcur, e, nbuk);
    p2_part<<<(e + 8191) / 8192, 256, 0, stream>>>(ei, bcur, pairs, e);
    p3_build<<<nbuk, 256, 0, stream>>>(pairs, bbase, rp, dsc, esrc, n, e);
    wt_kernel<<<(2 * D * D + 255) / 256, 256, 0, stream>>>(W1, W2, Wt1, Wt2);

    int nbG = (n + 127) / 128;
    gemm_scale<<<nbG, 256, 0, stream>>>(x, Wt1, dsc, A, n);
    agg_kernel<<<(n + 7) / 8, 256, 0, stream>>>(A, dsc, b1, rp, esrc, B, n);
    gemm_scale<<<nbG, 256, 0, stream>>>(B, Wt2, dsc, A, n);
    agg_kernel<<<(n + 7) / 8, 256, 0, stream>>>(A, dsc, b2, rp, esrc, out, n);
}

// Round 11
// 300.298 us; speedup vs baseline: 1.2837x; 1.0825x over previous
//
#include <hip/hip_runtime.h>
#include <hip/hip_fp16.h>

#define D 96
#define BSH 8          // 256 nodes per bucket
#define BNODES 256
#define MAXBUK 512     // supports n <= 131072

// ---------------- bucket-partition CSR build ----------------

// P1: global bucket histogram (LDS-aggregated), grid-stride
__global__ __launch_bounds__(256) void p1_hist(const int* __restrict__ ei,
                                               int* __restrict__ bcnt, int e) {
    __shared__ int h[MAXBUK];
    for (int i = threadIdx.x; i < MAXBUK; i += 256) h[i] = 0;
    __syncthreads();
    for (int i = blockIdx.x * 256 + threadIdx.x; i < e; i += gridDim.x * 256)
        atomicAdd(&h[ei[e + i] >> BSH], 1);
    __syncthreads();
    for (int i = threadIdx.x; i < MAXBUK; i += 256)
        if (h[i]) atomicAdd(&bcnt[i], h[i]);
}

// P1b: exclusive scan of bucket counts -> bbase[MAXBUK+1]; init reservation cursors
__global__ void p1_scan(const int* __restrict__ bcnt, int* __restrict__ bbase,
                        int* __restrict__ bcur, int e, int nbuk) {
    __shared__ int s[MAXBUK];
    int t = threadIdx.x;
    int v = (t < nbuk) ? bcnt[t] : 0;
    s[t] = v;
    __syncthreads();
    for (int off = 1; off < MAXBUK; off <<= 1) {
        int u = (t >= off) ? s[t - off] : 0;
        __syncthreads();
        s[t] += u;
        __syncthreads();
    }
    int ex = s[t] - v;           // for t >= nbuk this equals e (empty buckets)
    bbase[t] = ex;
    bcur[t] = ex;
    if (t == MAXBUK - 1) bbase[MAXBUK] = e;
}

// P2: partition edges into bucket-grouped (dst,src) pairs; per-block chunk reservation
__global__ __launch_bounds__(256) void p2_part(const int* __restrict__ ei,
                                               int* __restrict__ bcur,
                                               int2* __restrict__ pairs, int e) {
    __shared__ int h[MAXBUK];
    __shared__ int base[MAXBUK];
    __shared__ int offs[MAXBUK];
    const int CHUNK = 2048;
    int begin = blockIdx.x * CHUNK;
    int endc = min(begin + CHUNK, e);
    for (int i = threadIdx.x; i < MAXBUK; i += 256) h[i] = 0;
    __syncthreads();
    for (int i = begin + threadIdx.x; i < endc; i += 256)
        atomicAdd(&h[ei[e + i] >> BSH], 1);
    __syncthreads();
    for (int i = threadIdx.x; i < MAXBUK; i += 256) {
        int c = h[i];
        base[i] = c ? atomicAdd(&bcur[i], c) : 0;
        offs[i] = 0;
    }
    __syncthreads();
    for (int i = begin + threadIdx.x; i < endc; i += 256) {
        int d = ei[e + i], sv = ei[i];
        int b = d >> BSH;
        int r = atomicAdd(&offs[b], 1);
        pairs[base[b] + r] = make_int2(d, sv);
    }
}

// P3: one block per bucket (256 nodes, 1 node/thread): degrees + scan in LDS
//     -> rp, dis, esrc (bucket region is L2-hot)
__global__ __launch_bounds__(256) void p3_build(const int2* __restrict__ pairs,
                                                const int* __restrict__ bbase,
                                                int* __restrict__ rp, float* __restrict__ dis,
                                                int* __restrict__ esrc, int n, int e) {
    __shared__ int deg[BNODES];
    __shared__ int cur[BNODES];
    __shared__ int ps[256];
    int b = blockIdx.x;
    int node0 = b << BSH;
    int t = threadIdx.x;
    int pbeg = bbase[b], pend = bbase[b + 1];
    deg[t] = 0;
    __syncthreads();
    for (int i = pbeg + t; i < pend; i += 256)
        atomicAdd(&deg[pairs[i].x - node0], 1);
    __syncthreads();
    int pv = deg[t];
    ps[t] = pv;
    __syncthreads();
    for (int off = 1; off < 256; off <<= 1) {
        int u = (t >= off) ? ps[t - off] : 0;
        __syncthreads();
        ps[t] += u;
        __syncthreads();
    }
    int ex = ps[t] - pv;                 // exclusive base of node t within bucket
    cur[t] = ex;
    int n0 = node0 + t;
    if (n0 < n) { rp[n0] = pbeg + ex; dis[n0] = rsqrtf((float)(pv + 1)); }
    if (b == 0 && t == 0) rp[n] = e;
    __syncthreads();
    for (int i = pbeg + t; i < pend; i += 256) {
        int2 p = pairs[i];
        int r = atomicAdd(&cur[p.x - node0], 1);
        esrc[pbeg + r] = p.y;
    }
}

// ---------------- one-shot W transpose: Wt[c][k] = W[k][c] ----------------

__global__ void wt_kernel(const float* __restrict__ W1, const float* __restrict__ W2,
                          float* __restrict__ Wt1, float* __restrict__ Wt2) {
    int i = blockIdx.x * 256 + threadIdx.x;
    if (i < D * D) {
        int k = i / D, c = i % D;
        Wt1[c * D + k] = W1[i];
        Wt2[c * D + k] = W2[i];
    }
}

// ---------------- hs(fp16) = dis[row] * (X @ W) ----------------
// Structure unchanged from R10 except fp16 output (halves agg gather traffic).

#define KC 32
#define XS_S 36
#define WT_S 36

__global__ __launch_bounds__(256) void gemm_scale(const float* __restrict__ X,
                                                  const float* __restrict__ Wt,
                                                  const float* __restrict__ dis,
                                                  __half* __restrict__ out, int n) {
    __shared__ float xs[128 * XS_S];   // 18432 B
    __shared__ float wt[96 * WT_S];    // 13824 B
    int t = threadIdx.x;
    int row0 = blockIdx.x * 128;
    int rg = t & 15;      // rows rg*8 .. +7
    int cg = t >> 4;      // cols cg*6 .. +5
    float acc[8][6] = {};

    for (int kc = 0; kc < D; kc += KC) {
        for (int i = t; i < 96 * 8; i += 256) {            // wt chunk
            int c = i >> 3, c4 = i & 7;
            float4 v = *(const float4*)&Wt[c * D + kc + c4 * 4];
            *(float4*)&wt[c * WT_S + c4 * 4] = v;
        }
        for (int i = t; i < 128 * 8; i += 256) {           // xs chunk (swizzled)
            int r = i >> 3, c4 = i & 7;
            int gr = row0 + r;
            float4 v = (gr < n) ? *(const float4*)&X[(size_t)gr * D + kc + c4 * 4]
                                : make_float4(0.f, 0.f, 0.f, 0.f);
            *(float4*)&xs[r * XS_S + 4 * (c4 ^ ((r >> 3) & 7))] = v;
        }
        __syncthreads();
        #pragma unroll
        for (int k4 = 0; k4 < 8; ++k4) {
            float4 a[8], b[6];
            int xk = 4 * (k4 ^ (rg & 7));
            #pragma unroll
            for (int i = 0; i < 8; ++i)
                a[i] = *(const float4*)&xs[(rg * 8 + i) * XS_S + xk];
            #pragma unroll
            for (int j = 0; j < 6; ++j)
                b[j] = *(const float4*)&wt[(cg * 6 + j) * WT_S + k4 * 4];
            #pragma unroll
            for (int i = 0; i < 8; ++i)
                #pragma unroll
                for (int j = 0; j < 6; ++j) {
                    acc[i][j] += a[i].x * b[j].x;
                    acc[i][j] += a[i].y * b[j].y;
                    acc[i][j] += a[i].z * b[j].z;
                    acc[i][j] += a[i].w * b[j].w;
                }
        }
        __syncthreads();
    }
    #pragma unroll
    for (int i = 0; i < 8; ++i) {
        int gr = row0 + rg * 8 + i;
        if (gr < n) {
            float dsc = dis[gr];
            #pragma unroll
            for (int j = 0; j < 6; ++j)
                out[(size_t)gr * D + cg * 6 + j] = __float2half(dsc * acc[i][j]);
        }
    }
}

// ---------------- out = relu(dis[i]*(hs[i] + sum_{e:dst=i} hs[src]) + b) ----------------
// 24 active lanes per 32-lane node-group; fp16 rows: one float2 (4 halves) per lane.
// 2-way edge unroll with dual accumulators for memory-level parallelism.

__global__ __launch_bounds__(256) void agg_kernel(const __half* __restrict__ hs,
                                                  const float* __restrict__ dis,
                                                  const float* __restrict__ bias,
                                                  const int* __restrict__ rp,
                                                  const int* __restrict__ esrc,
                                                  float* __restrict__ out, int n) {
    int lane = threadIdx.x & 31;
    int node = blockIdx.x * 8 + (threadIdx.x >> 5);
    if (node >= n || lane >= 24) return;
    float2 raw = ((const float2*)(hs + (size_t)node * D))[lane];   // self-loop, 4 halves
    __half2* hp = (__half2*)&raw;
    float2 l0 = __half22float2(hp[0]), l1 = __half22float2(hp[1]);
    float s0 = l0.x, s1 = l0.y, s2 = l1.x, s3 = l1.y;
    float t0 = 0.f, t1 = 0.f, t2 = 0.f, t3 = 0.f;
    int beg = rp[node], end = rp[node + 1];
    int e = beg;
    for (; e + 1 < end; e += 2) {
        float2 r0 = ((const float2*)(hs + (size_t)esrc[e] * D))[lane];
        float2 r1 = ((const float2*)(hs + (size_t)esrc[e + 1] * D))[lane];
        __half2* h0 = (__half2*)&r0;
        __half2* h1 = (__half2*)&r1;
        float2 a0 = __half22float2(h0[0]), a1 = __half22float2(h0[1]);
        float2 b0 = __half22float2(h1[0]), b1 = __half22float2(h1[1]);
        s0 += a0.x; s1 += a0.y; s2 += a1.x; s3 += a1.y;
        t0 += b0.x; t1 += b0.y; t2 += b1.x; t3 += b1.y;
    }
    if (e < end) {
        float2 r0 = ((const float2*)(hs + (size_t)esrc[e] * D))[lane];
        __half2* h0 = (__half2*)&r0;
        float2 a0 = __half22float2(h0[0]), a1 = __half22float2(h0[1]);
        s0 += a0.x; s1 += a0.y; s2 += a1.x; s3 += a1.y;
    }
    float dsc = dis[node];
    float4 b = ((const float4*)bias)[lane];
    float4 o;
    o.x = fmaxf(dsc * (s0 + t0) + b.x, 0.f);
    o.y = fmaxf(dsc * (s1 + t1) + b.y, 0.f);
    o.z = fmaxf(dsc * (s2 + t2) + b.z, 0.f);
    o.w = fmaxf(dsc * (s3 + t3) + b.w, 0.f);
    ((float4*)(out + (size_t)node * D))[lane] = o;
}

extern "C" void kernel_launch(void* const* d_in, const int* in_sizes, int n_in,
                              void* d_out, int out_size, void* d_ws, size_t ws_size,
                              hipStream_t stream) {
    const float* x  = (const float*)d_in[0];
    const int*   ei = (const int*)d_in[1];
    const float* W1 = (const float*)d_in[2];
    const float* b1 = (const float*)d_in[3];
    const float* W2 = (const float*)d_in[4];
    const float* b2 = (const float*)d_in[5];
    float* out = (float*)d_out;
    int n = in_sizes[0] / D;
    int e = in_sizes[1] / 2;
    int nbuk = (n + BNODES - 1) >> BSH;

    char* ws = (char*)d_ws;
    size_t off = 0;
    auto take = [&](size_t bytes) {
        char* p = ws + off;
        off += (bytes + 511) & ~511ULL;
        return p;
    };
    int*    bcnt  = (int*)take(MAXBUK * 4);
    int*    bbase = (int*)take((MAXBUK + 1) * 4);
    int*    bcur  = (int*)take(MAXBUK * 4);
    int2*   pairs = (int2*)take((size_t)e * 8);
    int*    rp    = (int*)take((size_t)(n + 1) * 4);
    float*  dsc   = (float*)take((size_t)n * 4);
    float*  Wt1   = (float*)take((size_t)D * D * 4);
    float*  Wt2   = (float*)take((size_t)D * D * 4);
    int*    esrc  = (int*)take((size_t)e * 4);
    __half* A     = (__half*)take((size_t)n * D * 2);
    float*  B     = (float*)take((size_t)n * D * 4);

    hipMemsetAsync(bcnt, 0, MAXBUK * 4, stream);

    p1_hist<<<512, 256, 0, stream>>>(ei, bcnt, e);
    p1_scan<<<1, MAXBUK, 0, stream>>>(bcnt, bbase, bcur, e, nbuk);
    p2_part<<<(e + 2047) / 2048, 256, 0, stream>>>(ei, bcur, pairs, e);
    p3_build<<<nbuk, 256, 0, stream>>>(pairs, bbase, rp, dsc, esrc, n, e);
    wt_kernel<<<(2 * D * D + 255) / 256, 256, 0, stream>>>(W1, W2, Wt1, Wt2);

    int nbG = (n + 127) / 128;
    gemm_scale<<<nbG, 256, 0, stream>>>(x, Wt1, dsc, A, n);
    agg_kernel<<<(n + 7) / 8, 256, 0, stream>>>(A, dsc, b1, rp, esrc, B, n);
    gemm_scale<<<nbG, 256, 0, stream>>>(B, Wt2, dsc, A, n);
    agg_kernel<<<(n + 7) / 8, 256, 0, stream>>>(A, dsc, b2, rp, esrc, out, n);
}